// Round 5
// baseline (109.389 us; speedup 1.0000x reference)
//
#include <hip/hip_runtime.h>

#define BATCH 8192
#define DIM   512
#define NSB   32                  // 256-wide superblocks
#define NTILES (NSB*(NSB+1)/2)    // 528 (I,J) pairs, I <= J

typedef __attribute__((ext_vector_type(8))) _Float16 half8;
typedef __attribute__((ext_vector_type(4))) float f32x4;
typedef unsigned short ushort_t;

// async global->LDS, 16B per lane; LDS dest = wave-uniform base + lane*16
__device__ __forceinline__ void gload_lds16(const ushort_t* g, ushort_t* l){
  __builtin_amdgcn_global_load_lds(
      (const __attribute__((address_space(1))) void*)g,
      (__attribute__((address_space(3))) void*)l, 16, 0, 0);
}

// --- Kernel 1: L2-normalize rows, emit fp16, chunk-XOR-swizzled layout ------
// Within each row's 64B k-group (32 f16), 16B chunk c stored at c ^ ((row>>1)&3).
// k_gemm stages linearly (global_load_lds) and applies the same XOR on ds_read
// (involution, rule #21) -> conflict-free (verified: 8.5M -> 0).
__global__ __launch_bounds__(256) void k_normalize(const float* __restrict__ x,
                                                   ushort_t* __restrict__ q){
  const int row  = blockIdx.x * 4 + (threadIdx.x >> 6);
  const int lane = threadIdx.x & 63;
  const float* xr = x + (size_t)row * DIM + lane * 8;
  float4 a = *(const float4*)xr;
  float4 b = *(const float4*)(xr + 4);
  float s = a.x*a.x + a.y*a.y + a.z*a.z + a.w*a.w
          + b.x*b.x + b.y*b.y + b.z*b.z + b.w*b.w;
  #pragma unroll
  for (int m = 1; m < 64; m <<= 1) s += __shfl_xor(s, m);
  const float inv = 1.0f / fmaxf(sqrtf(s), 1e-12f);
  float f[8] = {a.x, a.y, a.z, a.w, b.x, b.y, b.z, b.w};
  half8 h;
  #pragma unroll
  for (int e = 0; e < 8; e++) h[e] = (_Float16)(f[e] * inv);
  const int grp = lane >> 2;
  const int ch  = lane & 3;
  const int sw  = (row >> 1) & 3;
  size_t off = (size_t)row * DIM + grp * 32 + (size_t)(ch ^ sw) * 8;
  *(half8*)(q + off) = h;
}

// --- Kernel 2: 256x256 tiles over the superblock triangle -------------------
// 8 waves (2x4), wave tile 128x64 = 8x4 frags of 16x16x32. BK=64 staged as
// 2 k-half sub-panels [256][32] (round-4-verified swizzle per sub-panel).
// Double-buffered, stage-at-top + counted drain (vmcnt(0) one full tile after
// issue) with raw s_barrier. 512 blocks; hw blocks 0..15 take a second tile.
__global__ __launch_bounds__(512, 2) void k_gemm(const ushort_t* __restrict__ q,
                                                 const int* __restrict__ labels,
                                                 float* __restrict__ ppos,
                                                 float* __restrict__ ptot){
  __shared__ ushort_t sA[2][16384];   // [buf][kh*8192 + row*32 + col]
  __shared__ ushort_t sB[2][16384];
  __shared__ int labI[256], labJ[256];

  const int hwb  = blockIdx.x;
  const int t    = threadIdx.x;
  const int lane = t & 63;
  const int w    = t >> 6;            // 0..7
  const int wr   = w >> 2;            // 0..1
  const int wc   = w & 3;             // 0..3
  const int lrow = lane & 15;
  const int g    = lane >> 4;
  const int gs   = (g ^ ((lrow >> 1) & 3)) * 8;   // swizzled chunk
  const int dW   = w * 512;           // wave-uniform LDS elem base per shot

  int ra[8], rb[4];
  #pragma unroll
  for (int m = 0; m < 8; m++) ra[m] = (wr * 128 + m * 16 + lrow) * 32 + gs;
  #pragma unroll
  for (int n = 0; n < 4; n++) rb[n] = (wc * 64 + n * 16 + lrow) * 32 + gs;

  int tiles[2]; int nt = 1;
  tiles[0] = (hwb & 7) * 64 + (hwb >> 3);        // XCD-contiguous logical id
  if (hwb < 16) tiles[nt++] = 512 + hwb;         // 2 extra tiles per XCD

  for (int ti = 0; ti < nt; ++ti){
    const int tile = tiles[ti];
    // decode tile -> (I <= J); start(I) = I*(65-I)/2
    int I = (int)(32.5f - sqrtf(1056.25f - 2.0f * (float)tile));
    while ((I + 1) * (64 - I) / 2 <= tile) I++;
    while (I * (65 - I) / 2 > tile) I--;
    const int J = I + (tile - I * (65 - I) / 2);
    const bool mirror = (J > I);
    const int rowbase = I * 256, colbase = J * 256;

    const size_t gA = (size_t)(rowbase + (t >> 2)) * DIM + (t & 3) * 8;
    const size_t gB = (size_t)(colbase + (t >> 2)) * DIM + (t & 3) * 8;

#define STAGE(BUF, KK) do {                                               \
    const ushort_t* ga = q + gA + (KK);                                   \
    const ushort_t* gb = q + gB + (KK);                                   \
    gload_lds16(ga,                  sA[BUF] + dW);                       \
    gload_lds16(ga + 128 * DIM,      sA[BUF] + dW + 4096);                \
    gload_lds16(ga + 32,             sA[BUF] + dW + 8192);                \
    gload_lds16(ga + 128 * DIM + 32, sA[BUF] + dW + 12288);               \
    gload_lds16(gb,                  sB[BUF] + dW);                       \
    gload_lds16(gb + 128 * DIM,      sB[BUF] + dW + 4096);                \
    gload_lds16(gb + 32,             sB[BUF] + dW + 8192);                \
    gload_lds16(gb + 128 * DIM + 32, sB[BUF] + dW + 12288);               \
  } while (0)

    __builtin_amdgcn_s_barrier();       // prev tile's LDS readers done
    if (t < 256) labI[t] = labels[rowbase + t];
    else         labJ[t - 256] = labels[colbase + (t - 256)];
    STAGE(0, 0);
    asm volatile("s_waitcnt vmcnt(0) lgkmcnt(0)" ::: "memory");
    __builtin_amdgcn_s_barrier();

    f32x4 acc[8][4];
    #pragma unroll
    for (int m = 0; m < 8; m++)
      #pragma unroll
      for (int n = 0; n < 4; n++)
        acc[m][n] = (f32x4){0.f, 0.f, 0.f, 0.f};

    #pragma unroll
    for (int kt = 0; kt < 8; kt++){
      const int cur = kt & 1;
      if (kt < 7) STAGE(cur ^ 1, (kt + 1) * 64);   // issue next tile early
      #pragma unroll
      for (int kh = 0; kh < 2; kh++){
        half8 bv[4], av[8];
        #pragma unroll
        for (int n = 0; n < 4; n++) bv[n] = *(const half8*)(sB[cur] + kh * 8192 + rb[n]);
        #pragma unroll
        for (int m = 0; m < 8; m++) av[m] = *(const half8*)(sA[cur] + kh * 8192 + ra[m]);
        __builtin_amdgcn_s_setprio(1);
        #pragma unroll
        for (int m = 0; m < 8; m++)
          #pragma unroll
          for (int n = 0; n < 4; n++)
            acc[m][n] = __builtin_amdgcn_mfma_f32_16x16x32_f16(av[m], bv[n], acc[m][n], 0, 0, 0);
        __builtin_amdgcn_s_setprio(0);
      }
      asm volatile("s_waitcnt vmcnt(0)" ::: "memory");   // next buffer landed
      __builtin_amdgcn_s_barrier();
    }
#undef STAGE

    const int i0 = rowbase + wr * 128;
    const int j0 = colbase + wc * 64;

    int li_[8][4], lj_[4];
    #pragma unroll
    for (int m = 0; m < 8; m++)
      #pragma unroll
      for (int e = 0; e < 4; e++)
        li_[m][e] = labI[wr * 128 + m * 16 + g * 4 + e];
    #pragma unroll
    for (int n = 0; n < 4; n++)
      lj_[n] = labJ[wc * 64 + n * 16 + lrow];

    const float invT = 14.285714285714286f;  // 1/0.07
    #pragma unroll
    for (int m = 0; m < 8; m++)
      #pragma unroll
      for (int n = 0; n < 4; n++)
        #pragma unroll
        for (int e = 0; e < 4; e++){
          int i = i0 + m * 16 + g * 4 + e;
          int j = j0 + n * 16 + lrow;
          acc[m][n][e] = (i == j) ? 0.0f : __expf(acc[m][n][e] * invT);
        }

    // row sums -> slot J*4 + wc  (slots [4S,128) for rows of superblock S)
    {
      float* pp = ppos + (size_t)(J * 4 + wc) * BATCH;
      float* pt = ptot + (size_t)(J * 4 + wc) * BATCH;
      #pragma unroll
      for (int m = 0; m < 8; m++){
        float tr[4] = {0, 0, 0, 0}, pr[4] = {0, 0, 0, 0};
        #pragma unroll
        for (int n = 0; n < 4; n++){
          int lj = lj_[n];
          #pragma unroll
          for (int e = 0; e < 4; e++){
            float v = acc[m][n][e];
            tr[e] += v;
            pr[e] += (li_[m][e] == lj) ? v : 0.0f;
          }
        }
        #pragma unroll
        for (int s = 1; s < 16; s <<= 1){
          #pragma unroll
          for (int e = 0; e < 4; e++){
            tr[e] += __shfl_xor(tr[e], s);
            pr[e] += __shfl_xor(pr[e], s);
          }
        }
        if (lrow == 0){
          int ib = i0 + m * 16 + g * 4;
          #pragma unroll
          for (int e = 0; e < 4; e++){
            pt[ib + e] = tr[e];
            pp[ib + e] = pr[e];
          }
        }
      }
    }

    // col sums via symmetry -> slots I*4 + wr*2 + h  (slots [0,4S))
    if (mirror){
      #pragma unroll
      for (int h = 0; h < 2; h++){
        float* pp = ppos + (size_t)(I * 4 + wr * 2 + h) * BATCH;
        float* pt = ptot + (size_t)(I * 4 + wr * 2 + h) * BATCH;
        #pragma unroll
        for (int n = 0; n < 4; n++){
          float ts = 0.f, ps = 0.f;
          int lj = lj_[n];
          #pragma unroll
          for (int m = h * 4; m < h * 4 + 4; m++)
            #pragma unroll
            for (int e = 0; e < 4; e++){
              float v = acc[m][n][e];
              ts += v;
              ps += (li_[m][e] == lj) ? v : 0.0f;
            }
          ts += __shfl_xor(ts, 16); ps += __shfl_xor(ps, 16);
          ts += __shfl_xor(ts, 32); ps += __shfl_xor(ps, 32);
          if (lane < 16){
            int j = j0 + n * 16 + lane;
            pt[j] = ts;
            pp[j] = ps;
          }
        }
      }
    }
  }
}

// --- Kernel 3: per-row loss, per-block partial sum --------------------------
__global__ __launch_bounds__(256) void k_rowloss(const float* __restrict__ ppos,
                                                 const float* __restrict__ ptot,
                                                 float* __restrict__ bsum){
  const int i = blockIdx.x * 256 + threadIdx.x;
  float p = 0.f, t = 0.f;
  for (int c = 0; c < 128; c++){
    p += ppos[(size_t)c * BATCH + i];
    t += ptot[(size_t)c * BATCH + i];
  }
  float loss = -logf(p / (t + 1e-8f));
  float v = loss;
  #pragma unroll
  for (int s = 1; s < 64; s <<= 1) v += __shfl_xor(v, s);
  __shared__ float ws4[4];
  if ((threadIdx.x & 63) == 0) ws4[threadIdx.x >> 6] = v;
  __syncthreads();
  if (threadIdx.x == 0) bsum[blockIdx.x] = ws4[0] + ws4[1] + ws4[2] + ws4[3];
}

// --- Kernel 4: final mean ---------------------------------------------------
__global__ __launch_bounds__(64) void k_final(const float* __restrict__ bsum,
                                              float* __restrict__ out){
  float v = (threadIdx.x < 32) ? bsum[threadIdx.x] : 0.f;
  #pragma unroll
  for (int s = 1; s < 64; s <<= 1) v += __shfl_xor(v, s);
  if (threadIdx.x == 0) out[0] = v * (1.0f / 8192.0f);
}

extern "C" void kernel_launch(void* const* d_in, const int* in_sizes, int n_in,
                              void* d_out, int out_size, void* d_ws, size_t ws_size,
                              hipStream_t stream){
  const float* x      = (const float*)d_in[0];
  const int*   labels = (const int*)d_in[1];
  float*       out    = (float*)d_out;

  char* ws = (char*)d_ws;
  ushort_t* q  = (ushort_t*)ws;                      //  8,388,608 B (8192x512 f16)
  float* ppos  = (float*)(ws + 8388608);             //  4,194,304 B (128 x 8192 f32)
  float* ptot  = (float*)(ws + 8388608 + 4194304);   //  4,194,304 B
  float* bsum  = (float*)(ws + 8388608 + 8388608);   //        128 B

  k_normalize<<<BATCH / 4, 256, 0, stream>>>(x, q);
  k_gemm<<<512, 512, 0, stream>>>(q, labels, ppos, ptot);
  k_rowloss<<<BATCH / 256, 256, 0, stream>>>(ppos, ptot, bsum);
  k_final<<<1, 64, 0, stream>>>(bsum, out);
}

// Round 6
// 95.932 us; speedup vs baseline: 1.1403x; 1.1403x over previous
//
#include <hip/hip_runtime.h>

#define BATCH 8192
#define DIM   512
#define NTILES 528                 // (I,J), 0 <= I <= J < 32, 256x256 tiles

typedef __attribute__((ext_vector_type(8))) _Float16 half8;
typedef __attribute__((ext_vector_type(4))) float f32x4;
typedef unsigned short ushort_t;

// async global->LDS, 16B per lane; LDS dest = wave-uniform base + lane*16
__device__ __forceinline__ void gload_lds16(const ushort_t* g, ushort_t* l){
  __builtin_amdgcn_global_load_lds(
      (const __attribute__((address_space(1))) void*)g,
      (__attribute__((address_space(3))) void*)l, 16, 0, 0);
}

// --- Kernel 1: L2-normalize rows -> fp16, chunk-XOR-swizzled layout ---------
// Row = 8 units of 128B; 16B chunk c of each unit stored at c ^ (row&7).
// k_gemm stages linearly (global_load_lds) and applies the same XOR on
// ds_read (involution, rule #21) -> 2 lanes/bank-slot = conflict-free.
__global__ __launch_bounds__(256) void k_normalize(const float* __restrict__ x,
                                                   ushort_t* __restrict__ q){
  const int row  = blockIdx.x * 4 + (threadIdx.x >> 6);
  const int lane = threadIdx.x & 63;
  const int u = lane >> 3, c = lane & 7;
  const float* xr = x + (size_t)row * DIM + u * 64 + c * 8;
  float4 a = *(const float4*)xr;
  float4 b = *(const float4*)(xr + 4);
  float s = a.x*a.x + a.y*a.y + a.z*a.z + a.w*a.w
          + b.x*b.x + b.y*b.y + b.z*b.z + b.w*b.w;
  #pragma unroll
  for (int m = 1; m < 64; m <<= 1) s += __shfl_xor(s, m);
  const float inv = 1.0f / fmaxf(sqrtf(s), 1e-12f);
  float f[8] = {a.x, a.y, a.z, a.w, b.x, b.y, b.z, b.w};
  half8 h;
  #pragma unroll
  for (int e = 0; e < 8; e++) h[e] = (_Float16)(f[e] * inv);
  *(half8*)(q + (size_t)row * DIM + u * 64 + (size_t)(c ^ (row & 7)) * 8) = h;
}

// --- Kernel 2: 256x256 tiles over superblock triangle, 4-phase schedule -----
// 8 waves (2x4), wave tile 128x64 = 8x4 frags of 16x16x32 f16. BK=64 dbuf
// (panels [256][64], 128KB LDS). Per K-tile: 4 quadrant phases (Z-order),
// staging for the next K-tile issued in ph1/ph2, single __syncthreads drain
// at the tile boundary (loads are >=2 phases old -> drain ~free).
__global__ __launch_bounds__(512, 2) void k_gemm(const ushort_t* __restrict__ q,
                                                 const int* __restrict__ labels,
                                                 float* __restrict__ ppos,
                                                 float* __restrict__ ptot){
  __shared__ ushort_t sA[2][256 * 64];   // 2 x 32 KB
  __shared__ ushort_t sB[2][256 * 64];
  __shared__ int labI[256], labJ[256];

  // XCD swizzle: 528 = 8 x 66, bijective
  const int bid = (blockIdx.x & 7) * 66 + (blockIdx.x >> 3);
  int I = (int)(32.5f - sqrtf(1056.25f - 2.0f * (float)bid));
  while ((I + 1) * (64 - I) / 2 <= bid) I++;
  while (I * (65 - I) / 2 > bid) I--;
  const int J = I + (bid - I * (65 - I) / 2);
  const bool mirror = (J > I);
  const int rowbase = I * 256, colbase = J * 256;

  const int t    = threadIdx.x;
  const int lane = t & 63;
  const int w    = t >> 6;            // 0..7
  const int wr   = w >> 2;            // 0..1
  const int wc   = w & 3;             // 0..3
  const int lrow = lane & 15;
  const int g    = lane >> 4;
  const int dW   = w * 512;           // elems: wave's 1KB slice per 8KB shot

  // ds_read offsets (elems): row*64 + ((kh*4+g)^(lrow&7))*8
  const int cs0 = ((g)     ^ (lrow & 7)) * 8;
  const int cs1 = ((4 + g) ^ (lrow & 7)) * 8;
  int ra[8], rb[4];
  #pragma unroll
  for (int m = 0; m < 8; m++) ra[m] = (wr * 128 + m * 16 + lrow) * 64;
  #pragma unroll
  for (int n = 0; n < 4; n++) rb[n] = (wc * 64 + n * 16 + lrow) * 64;

  // staging sources: thread t covers row (t>>3), phys chunk (t&7) per shot
  const ushort_t* srcA = q + (size_t)(rowbase + (t >> 3)) * DIM + (t & 7) * 8;
  const ushort_t* srcB = q + (size_t)(colbase + (t >> 3)) * DIM + (t & 7) * 8;

#define STAGE_A(BUF, KT) do{                                              \
    _Pragma("unroll") for (int s_ = 0; s_ < 4; s_++)                      \
      gload_lds16(srcA + (size_t)s_ * 64 * DIM + (KT) * 64,               \
                  sA[BUF] + s_ * 4096 + dW); }while(0)
#define STAGE_B(BUF, KT) do{                                              \
    _Pragma("unroll") for (int s_ = 0; s_ < 4; s_++)                      \
      gload_lds16(srcB + (size_t)s_ * 64 * DIM + (KT) * 64,               \
                  sB[BUF] + s_ * 4096 + dW); }while(0)

  half8 a_[4][2];        // current A half (mh), 32 VGPR
  half8 b_[2][2][2];     // both B halves [nh][ni][kh], 32 VGPR
  f32x4 acc[8][4];
  #pragma unroll
  for (int m = 0; m < 8; m++)
    #pragma unroll
    for (int n = 0; n < 4; n++)
      acc[m][n] = (f32x4){0.f, 0.f, 0.f, 0.f};

#define DSRD_A(P, MH) do{                                                 \
    _Pragma("unroll") for (int mi = 0; mi < 4; mi++){                     \
      const int ro = ra[(MH) * 4 + mi];                                   \
      a_[mi][0] = *(const half8*)((P) + ro + cs0);                        \
      a_[mi][1] = *(const half8*)((P) + ro + cs1); } }while(0)
#define DSRD_B(P, NH) do{                                                 \
    _Pragma("unroll") for (int ni = 0; ni < 2; ni++){                     \
      const int ro = rb[(NH) * 2 + ni];                                   \
      b_[NH][ni][0] = *(const half8*)((P) + ro + cs0);                    \
      b_[NH][ni][1] = *(const half8*)((P) + ro + cs1); } }while(0)
#define MMA(MH, NH) do{                                                   \
    __builtin_amdgcn_s_setprio(1);                                        \
    _Pragma("unroll") for (int kh = 0; kh < 2; kh++)                      \
      _Pragma("unroll") for (int mi = 0; mi < 4; mi++)                    \
        _Pragma("unroll") for (int ni = 0; ni < 2; ni++)                  \
          acc[(MH)*4+mi][(NH)*2+ni] = __builtin_amdgcn_mfma_f32_16x16x32_f16( \
              a_[mi][kh], b_[NH][ni][kh], acc[(MH)*4+mi][(NH)*2+ni], 0,0,0); \
    __builtin_amdgcn_s_setprio(0); }while(0)

  // prologue
  if (t < 256) labI[t] = labels[rowbase + t];
  else         labJ[t - 256] = labels[colbase + (t - 256)];
  STAGE_A(0, 0);
  STAGE_B(0, 0);
  __syncthreads();

  for (int kt = 0; kt < 8; ++kt){
    const int cur = kt & 1;
    const ushort_t* pA = sA[cur];
    const ushort_t* pB = sB[cur];
    // ph0: quadrant (0,0)
    DSRD_A(pA, 0); DSRD_B(pB, 0);
    __builtin_amdgcn_s_barrier();
    MMA(0, 0);
    __builtin_amdgcn_s_barrier();
    // ph1: quadrant (0,1); stage next A
    DSRD_B(pB, 1);
    if (kt < 7) STAGE_A(cur ^ 1, kt + 1);
    __builtin_amdgcn_s_barrier();
    MMA(0, 1);
    __builtin_amdgcn_s_barrier();
    // ph2: quadrant (1,1); stage next B
    DSRD_A(pA, 1);
    if (kt < 7) STAGE_B(cur ^ 1, kt + 1);
    __builtin_amdgcn_s_barrier();
    MMA(1, 1);
    __builtin_amdgcn_s_barrier();
    // ph3: quadrant (1,0) (operands resident)
    MMA(1, 0);
    __syncthreads();   // drains vmcnt (loads >=2 phases old) + aligns waves
  }
#undef STAGE_A
#undef STAGE_B
#undef DSRD_A
#undef DSRD_B
#undef MMA

  const int i0 = rowbase + wr * 128;
  const int j0 = colbase + wc * 64;

  int li_[8][4], lj_[4];
  #pragma unroll
  for (int m = 0; m < 8; m++)
    #pragma unroll
    for (int e = 0; e < 4; e++)
      li_[m][e] = labI[wr * 128 + m * 16 + g * 4 + e];
  #pragma unroll
  for (int n = 0; n < 4; n++)
    lj_[n] = labJ[wc * 64 + n * 16 + lrow];

  const float invT = 14.285714285714286f;  // 1/0.07
  #pragma unroll
  for (int m = 0; m < 8; m++)
    #pragma unroll
    for (int n = 0; n < 4; n++)
      #pragma unroll
      for (int e = 0; e < 4; e++){
        int i = i0 + m * 16 + g * 4 + e;
        int j = j0 + n * 16 + lrow;
        acc[m][n][e] = (i == j) ? 0.0f : __expf(acc[m][n][e] * invT);
      }

  // row sums -> slot J*4 + wc   (slots [4S,128) for rows of superblock S)
  {
    float* pp = ppos + (size_t)(J * 4 + wc) * BATCH;
    float* pt = ptot + (size_t)(J * 4 + wc) * BATCH;
    #pragma unroll
    for (int m = 0; m < 8; m++){
      float tr[4] = {0, 0, 0, 0}, pr[4] = {0, 0, 0, 0};
      #pragma unroll
      for (int n = 0; n < 4; n++){
        int lj = lj_[n];
        #pragma unroll
        for (int e = 0; e < 4; e++){
          float v = acc[m][n][e];
          tr[e] += v;
          pr[e] += (li_[m][e] == lj) ? v : 0.0f;
        }
      }
      #pragma unroll
      for (int s = 1; s < 16; s <<= 1){
        #pragma unroll
        for (int e = 0; e < 4; e++){
          tr[e] += __shfl_xor(tr[e], s);
          pr[e] += __shfl_xor(pr[e], s);
        }
      }
      if (lrow == 0){
        int ib = i0 + m * 16 + g * 4;
        #pragma unroll
        for (int e = 0; e < 4; e++){
          pt[ib + e] = tr[e];
          pp[ib + e] = pr[e];
        }
      }
    }
  }

  // col sums via symmetry -> slots I*4 + wr*2 + h  (slots [0,4S))
  if (mirror){
    #pragma unroll
    for (int h = 0; h < 2; h++){
      float* pp = ppos + (size_t)(I * 4 + wr * 2 + h) * BATCH;
      float* pt = ptot + (size_t)(I * 4 + wr * 2 + h) * BATCH;
      #pragma unroll
      for (int n = 0; n < 4; n++){
        float ts = 0.f, ps = 0.f;
        int lj = lj_[n];
        #pragma unroll
        for (int m = h * 4; m < h * 4 + 4; m++)
          #pragma unroll
          for (int e = 0; e < 4; e++){
            float v = acc[m][n][e];
            ts += v;
            ps += (li_[m][e] == lj) ? v : 0.0f;
          }
        ts += __shfl_xor(ts, 16); ps += __shfl_xor(ps, 16);
        ts += __shfl_xor(ts, 32); ps += __shfl_xor(ps, 32);
        if (lane < 16){
          int j = j0 + n * 16 + lane;
          pt[j] = ts;
          pp[j] = ps;
        }
      }
    }
  }
}

// --- Kernel 3: per-row loss, per-block partial sum --------------------------
__global__ __launch_bounds__(256) void k_rowloss(const float* __restrict__ ppos,
                                                 const float* __restrict__ ptot,
                                                 float* __restrict__ bsum){
  const int i = blockIdx.x * 256 + threadIdx.x;
  float p = 0.f, t = 0.f;
  for (int c = 0; c < 128; c++){
    p += ppos[(size_t)c * BATCH + i];
    t += ptot[(size_t)c * BATCH + i];
  }
  float loss = -logf(p / (t + 1e-8f));
  float v = loss;
  #pragma unroll
  for (int s = 1; s < 64; s <<= 1) v += __shfl_xor(v, s);
  __shared__ float ws4[4];
  if ((threadIdx.x & 63) == 0) ws4[threadIdx.x >> 6] = v;
  __syncthreads();
  if (threadIdx.x == 0) bsum[blockIdx.x] = ws4[0] + ws4[1] + ws4[2] + ws4[3];
}

// --- Kernel 4: final mean ---------------------------------------------------
__global__ __launch_bounds__(64) void k_final(const float* __restrict__ bsum,
                                              float* __restrict__ out){
  float v = (threadIdx.x < 32) ? bsum[threadIdx.x] : 0.f;
  #pragma unroll
  for (int s = 1; s < 64; s <<= 1) v += __shfl_xor(v, s);
  if (threadIdx.x == 0) out[0] = v * (1.0f / 8192.0f);
}

extern "C" void kernel_launch(void* const* d_in, const int* in_sizes, int n_in,
                              void* d_out, int out_size, void* d_ws, size_t ws_size,
                              hipStream_t stream){
  const float* x      = (const float*)d_in[0];
  const int*   labels = (const int*)d_in[1];
  float*       out    = (float*)d_out;

  char* ws = (char*)d_ws;
  ushort_t* q  = (ushort_t*)ws;                      //  8,388,608 B (8192x512 f16)
  float* ppos  = (float*)(ws + 8388608);             //  4,194,304 B (128 x 8192 f32)
  float* ptot  = (float*)(ws + 8388608 + 4194304);   //  4,194,304 B
  float* bsum  = (float*)(ws + 8388608 + 8388608);   //        128 B

  k_normalize<<<BATCH / 4, 256, 0, stream>>>(x, q);
  k_gemm<<<NTILES, 512, 0, stream>>>(q, labels, ppos, ptot);
  k_rowloss<<<BATCH / 256, 256, 0, stream>>>(ppos, ptot, bsum);
  k_final<<<1, 64, 0, stream>>>(bsum, out);
}

// Round 7
// 93.922 us; speedup vs baseline: 1.1647x; 1.0214x over previous
//
#include <hip/hip_runtime.h>

#define BATCH 8192
#define DIM   512
#define NTILES 528                 // (I,J), 0 <= I <= J < 32, 256x256 tiles

typedef __attribute__((ext_vector_type(8))) _Float16 half8;
typedef __attribute__((ext_vector_type(4))) float f32x4;
typedef unsigned short ushort_t;

// async global->LDS, 16B per lane; LDS dest = wave-uniform base + lane*16
__device__ __forceinline__ void gload_lds16(const ushort_t* g, ushort_t* l){
  __builtin_amdgcn_global_load_lds(
      (const __attribute__((address_space(1))) void*)g,
      (__attribute__((address_space(3))) void*)l, 16, 0, 0);
}

// VALU-only 16-lane-group sum via DPP (no LDS-pipe traffic)
template<int CTRL>
__device__ __forceinline__ float dpp_add(float v){
  int s = __builtin_amdgcn_update_dpp(0, __float_as_int(v), CTRL, 0xF, 0xF, true);
  return v + __int_as_float(s);
}
__device__ __forceinline__ float red16(float v){
  v = dpp_add<0xB1>(v);    // quad_perm [1,0,3,2]
  v = dpp_add<0x4E>(v);    // quad_perm [2,3,0,1]
  v = dpp_add<0x141>(v);   // row_half_mirror
  v = dpp_add<0x140>(v);   // row_mirror
  return v;
}

// --- Kernel 1: L2-normalize rows, emit fp16, chunk-XOR-swizzled layout ------
// Within each row's 64B k-group (32 f16), 16B chunk c stored at c ^ ((row>>1)&3).
// k_gemm stages linearly (global_load_lds) and applies the same XOR on ds_read
// (involution, rule #21) -> conflict-free (verified: 8.5M -> 0, rounds 3-5).
__global__ __launch_bounds__(256) void k_normalize(const float* __restrict__ x,
                                                   ushort_t* __restrict__ q){
  const int row  = blockIdx.x * 4 + (threadIdx.x >> 6);
  const int lane = threadIdx.x & 63;
  const float* xr = x + (size_t)row * DIM + lane * 8;
  float4 a = *(const float4*)xr;
  float4 b = *(const float4*)(xr + 4);
  float s = a.x*a.x + a.y*a.y + a.z*a.z + a.w*a.w
          + b.x*b.x + b.y*b.y + b.z*b.z + b.w*b.w;
  #pragma unroll
  for (int m = 1; m < 64; m <<= 1) s += __shfl_xor(s, m);
  const float inv = 1.0f / fmaxf(sqrtf(s), 1e-12f);
  float f[8] = {a.x, a.y, a.z, a.w, b.x, b.y, b.z, b.w};
  half8 h;
  #pragma unroll
  for (int e = 0; e < 8; e++) h[e] = (_Float16)(f[e] * inv);
  const int grp = lane >> 2;
  const int ch  = lane & 3;
  const int sw  = (row >> 1) & 3;
  size_t off = (size_t)row * DIM + grp * 32 + (size_t)(ch ^ sw) * 8;
  *(half8*)(q + off) = h;
}

// --- Kernel 2: 256x256 tiles, 4-buffer ring + counted vmcnt -----------------
// 8 waves (2x4), wave tile 128x64 = 8x4 frags of 16x16x32 f16. BK=32 per
// K-tile; 4 LDS buffers (128KB): K-tile kt uses buf[kt&3], staging of kt+3
// is issued during kt's phases (distance ~5 phases ~1800cyc >> HBM latency).
// Raw s_barrier only; ONE counted s_waitcnt vmcnt(8) per K-tile, placed at
// phase end BEFORE the barrier (collective guarantee). Never drains to 0 in
// steady state (m218: counted-vs-drain0 = +38-73%).
__global__ __launch_bounds__(512, 2) void k_gemm(const ushort_t* __restrict__ q,
                                                 const int* __restrict__ labels,
                                                 float* __restrict__ ppos,
                                                 float* __restrict__ ptot){
  __shared__ ushort_t sA[4][256 * 32];   // 4 x 16 KB
  __shared__ ushort_t sB[4][256 * 32];   // 4 x 16 KB
  __shared__ int labI[256], labJ[256];

  // XCD swizzle: 528 = 8 x 66, bijective
  const int bid = (blockIdx.x & 7) * 66 + (blockIdx.x >> 3);
  int I = (int)(32.5f - sqrtf(1056.25f - 2.0f * (float)bid));
  while ((I + 1) * (64 - I) / 2 <= bid) I++;
  while (I * (65 - I) / 2 > bid) I--;
  const int J = I + (bid - I * (65 - I) / 2);
  const bool mirror = (J > I);
  const int rowbase = I * 256, colbase = J * 256;

  const int t    = threadIdx.x;
  const int lane = t & 63;
  const int w    = t >> 6;            // 0..7
  const int wr   = w >> 2;            // 0..1
  const int wc   = w & 3;             // 0..3
  const int lrow = lane & 15;
  const int g    = lane >> 4;
  const int dW   = w * 512;           // wave-uniform LDS elem base per shot

  // swizzled ds_read offsets (elems): row*32 + ((g ^ ((lrow>>1)&3))*8)
  const int gs = (g ^ ((lrow >> 1) & 3)) * 8;
  int ra[8], rb[4];
  #pragma unroll
  for (int m = 0; m < 8; m++) ra[m] = (wr * 128 + m * 16 + lrow) * 32 + gs;
  #pragma unroll
  for (int n = 0; n < 4; n++) rb[n] = (wc * 64 + n * 16 + lrow) * 32 + gs;

  // staging: shot s covers rows s*128 + t/4, 16B chunk (t&3); global data is
  // pre-swizzled so linear staging + XOR read is the verified involution.
  const ushort_t* srcA = q + (size_t)(rowbase + (t >> 2)) * DIM + (t & 3) * 8;
  const ushort_t* srcB = q + (size_t)(colbase + (t >> 2)) * DIM + (t & 3) * 8;

#define STAGE_A(BUF, KT) do{                                              \
    gload_lds16(srcA + (KT) * 32,                 sA[BUF] + dW);          \
    gload_lds16(srcA + 128 * DIM + (KT) * 32,     sA[BUF] + dW + 4096);   \
  }while(0)
#define STAGE_B(BUF, KT) do{                                              \
    gload_lds16(srcB + (KT) * 32,                 sB[BUF] + dW);          \
    gload_lds16(srcB + 128 * DIM + (KT) * 32,     sB[BUF] + dW + 4096);   \
  }while(0)

  f32x4 acc[8][4];
  #pragma unroll
  for (int m = 0; m < 8; m++)
    #pragma unroll
    for (int n = 0; n < 4; n++)
      acc[m][n] = (f32x4){0.f, 0.f, 0.f, 0.f};

  // prologue: labels + stage K-tiles 0,1,2; wait only for K-tile 0 (vmcnt 8)
  if (t < 256) labI[t] = labels[rowbase + t];
  else         labJ[t - 256] = labels[colbase + (t - 256)];
  STAGE_A(0, 0); STAGE_B(0, 0);
  STAGE_A(1, 1); STAGE_B(1, 1);
  STAGE_A(2, 2); STAGE_B(2, 2);
  asm volatile("s_waitcnt vmcnt(8) lgkmcnt(0)" ::: "memory");
  asm volatile("s_barrier" ::: "memory");

  #pragma unroll
  for (int kt = 0; kt < 16; ++kt){
    const int cb = kt & 3;
    const int nb = (kt + 3) & 3;
    half8 av[4], bv[4];
    // ---- phase 0: read B (all) + A rows 0..63 of wave; stage A(kt+3)
    #pragma unroll
    for (int n = 0; n < 4; n++) bv[n] = *(const half8*)(sB[cb] + rb[n]);
    #pragma unroll
    for (int m = 0; m < 4; m++) av[m] = *(const half8*)(sA[cb] + ra[m]);
    if (kt < 13) STAGE_A(nb, kt + 3);
    asm volatile("s_barrier" ::: "memory");
    __builtin_amdgcn_s_setprio(1);
    #pragma unroll
    for (int m = 0; m < 4; m++)
      #pragma unroll
      for (int n = 0; n < 4; n++)
        acc[m][n] = __builtin_amdgcn_mfma_f32_16x16x32_f16(av[m], bv[n], acc[m][n], 0, 0, 0);
    __builtin_amdgcn_s_setprio(0);
    asm volatile("s_barrier" ::: "memory");
    // ---- phase 1: read A rows 64..127 of wave; stage B(kt+3)
    #pragma unroll
    for (int m = 0; m < 4; m++) av[m] = *(const half8*)(sA[cb] + ra[4 + m]);
    if (kt < 13) STAGE_B(nb, kt + 3);
    asm volatile("s_barrier" ::: "memory");
    __builtin_amdgcn_s_setprio(1);
    #pragma unroll
    for (int m = 0; m < 4; m++)
      #pragma unroll
      for (int n = 0; n < 4; n++)
        acc[4 + m][n] = __builtin_amdgcn_mfma_f32_16x16x32_f16(av[m], bv[n], acc[4 + m][n], 0, 0, 0);
    __builtin_amdgcn_s_setprio(0);
    // counted wait: guarantee K-tile kt+1 resident; newest 8 loads (kt+2,kt+3)
    // may stay in flight. Tail: fewer outstanding -> smaller counts.
    if (kt < 13)       asm volatile("s_waitcnt vmcnt(8)" ::: "memory");
    else if (kt == 13) asm volatile("s_waitcnt vmcnt(4)" ::: "memory");
    else if (kt == 14) asm volatile("s_waitcnt vmcnt(0)" ::: "memory");
    asm volatile("s_barrier" ::: "memory");
  }
#undef STAGE_A
#undef STAGE_B

  const int i0 = rowbase + wr * 128;
  const int j0 = colbase + wc * 64;

  int li_[8][4], lj_[4];
  #pragma unroll
  for (int m = 0; m < 8; m++)
    #pragma unroll
    for (int e = 0; e < 4; e++)
      li_[m][e] = labI[wr * 128 + m * 16 + g * 4 + e];
  #pragma unroll
  for (int n = 0; n < 4; n++)
    lj_[n] = labJ[wc * 64 + n * 16 + lrow];

  const float invT = 14.285714285714286f;  // 1/0.07
  #pragma unroll
  for (int m = 0; m < 8; m++)
    #pragma unroll
    for (int n = 0; n < 4; n++)
      #pragma unroll
      for (int e = 0; e < 4; e++){
        int i = i0 + m * 16 + g * 4 + e;
        int j = j0 + n * 16 + lrow;
        acc[m][n][e] = (i == j) ? 0.0f : __expf(acc[m][n][e] * invT);
      }

  // row sums -> slot J*4 + wc  (slots [4S,128) for rows of superblock S)
  // 16-lane reduce via DPP (VALU), not shfl/bpermute (LDS pipe).
  {
    float* pp = ppos + (size_t)(J * 4 + wc) * BATCH;
    float* pt = ptot + (size_t)(J * 4 + wc) * BATCH;
    #pragma unroll
    for (int m = 0; m < 8; m++){
      float tr[4] = {0, 0, 0, 0}, pr[4] = {0, 0, 0, 0};
      #pragma unroll
      for (int n = 0; n < 4; n++){
        int lj = lj_[n];
        #pragma unroll
        for (int e = 0; e < 4; e++){
          float v = acc[m][n][e];
          tr[e] += v;
          pr[e] += (li_[m][e] == lj) ? v : 0.0f;
        }
      }
      #pragma unroll
      for (int e = 0; e < 4; e++){
        tr[e] = red16(tr[e]);
        pr[e] = red16(pr[e]);
      }
      if (lrow == 0){
        int ib = i0 + m * 16 + g * 4;
        #pragma unroll
        for (int e = 0; e < 4; e++){
          pt[ib + e] = tr[e];
          pp[ib + e] = pr[e];
        }
      }
    }
  }

  // col sums via symmetry -> slots I*4 + wr*2 + h  (slots [0,4S))
  if (mirror){
    #pragma unroll
    for (int h = 0; h < 2; h++){
      float* pp = ppos + (size_t)(I * 4 + wr * 2 + h) * BATCH;
      float* pt = ptot + (size_t)(I * 4 + wr * 2 + h) * BATCH;
      #pragma unroll
      for (int n = 0; n < 4; n++){
        float ts = 0.f, ps = 0.f;
        int lj = lj_[n];
        #pragma unroll
        for (int m = h * 4; m < h * 4 + 4; m++)
          #pragma unroll
          for (int e = 0; e < 4; e++){
            float v = acc[m][n][e];
            ts += v;
            ps += (li_[m][e] == lj) ? v : 0.0f;
          }
        ts += __shfl_xor(ts, 16); ps += __shfl_xor(ps, 16);
        ts += __shfl_xor(ts, 32); ps += __shfl_xor(ps, 32);
        if (lane < 16){
          int j = j0 + n * 16 + lane;
          pt[j] = ts;
          pp[j] = ps;
        }
      }
    }
  }
}

// --- Kernel 3: per-row loss, per-block partial sum --------------------------
__global__ __launch_bounds__(256) void k_rowloss(const float* __restrict__ ppos,
                                                 const float* __restrict__ ptot,
                                                 float* __restrict__ bsum){
  const int i = blockIdx.x * 256 + threadIdx.x;
  float p = 0.f, t = 0.f;
  for (int c = 0; c < 128; c++){
    p += ppos[(size_t)c * BATCH + i];
    t += ptot[(size_t)c * BATCH + i];
  }
  float loss = -logf(p / (t + 1e-8f));
  float v = loss;
  #pragma unroll
  for (int s = 1; s < 64; s <<= 1) v += __shfl_xor(v, s);
  __shared__ float ws4[4];
  if ((threadIdx.x & 63) == 0) ws4[threadIdx.x >> 6] = v;
  __syncthreads();
  if (threadIdx.x == 0) bsum[blockIdx.x] = ws4[0] + ws4[1] + ws4[2] + ws4[3];
}

// --- Kernel 4: final mean ---------------------------------------------------
__global__ __launch_bounds__(64) void k_final(const float* __restrict__ bsum,
                                              float* __restrict__ out){
  float v = (threadIdx.x < 32) ? bsum[threadIdx.x] : 0.f;
  #pragma unroll
  for (int s = 1; s < 64; s <<= 1) v += __shfl_xor(v, s);
  if (threadIdx.x == 0) out[0] = v * (1.0f / 8192.0f);
}

extern "C" void kernel_launch(void* const* d_in, const int* in_sizes, int n_in,
                              void* d_out, int out_size, void* d_ws, size_t ws_size,
                              hipStream_t stream){
  const float* x      = (const float*)d_in[0];
  const int*   labels = (const int*)d_in[1];
  float*       out    = (float*)d_out;

  char* ws = (char*)d_ws;
  ushort_t* q  = (ushort_t*)ws;                      //  8,388,608 B (8192x512 f16)
  float* ppos  = (float*)(ws + 8388608);             //  4,194,304 B (128 x 8192 f32)
  float* ptot  = (float*)(ws + 8388608 + 4194304);   //  4,194,304 B
  float* bsum  = (float*)(ws + 8388608 + 8388608);   //        128 B

  k_normalize<<<BATCH / 4, 256, 0, stream>>>(x, q);
  k_gemm<<<NTILES, 512, 0, stream>>>(q, labels, ppos, ptot);
  k_rowloss<<<BATCH / 256, 256, 0, stream>>>(ppos, ptot, bsum);
  k_final<<<1, 64, 0, stream>>>(bsum, out);
}

// Round 8
// 59.552 us; speedup vs baseline: 1.8368x; 1.5771x over previous
//
#include <hip/hip_runtime.h>

#define BATCH 8192
#define DIM   512
#define NBLK  1056                 // (I,J): I in 0..31 (256-row sb), J in [2I,64) (128-col)

typedef __attribute__((ext_vector_type(2))) long long2_t;
typedef __attribute__((ext_vector_type(4))) float f32x4;
typedef unsigned short ushort_t;
typedef unsigned char  u8;

// async global->LDS, 16B per lane; LDS dest = wave-uniform base + lane*16
__device__ __forceinline__ void gload_lds16(const void* g, void* l){
  __builtin_amdgcn_global_load_lds(
      (const __attribute__((address_space(1))) void*)g,
      (__attribute__((address_space(3))) void*)l, 16, 0, 0);
}

// VALU-only 16-lane-group sum via DPP (verified r7)
template<int CTRL>
__device__ __forceinline__ float dpp_add(float v){
  int s = __builtin_amdgcn_update_dpp(0, __float_as_int(v), CTRL, 0xF, 0xF, true);
  return v + __int_as_float(s);
}
__device__ __forceinline__ float red16(float v){
  v = dpp_add<0xB1>(v);    // quad_perm [1,0,3,2]
  v = dpp_add<0x4E>(v);    // quad_perm [2,3,0,1]
  v = dpp_add<0x141>(v);   // row_half_mirror
  v = dpp_add<0x140>(v);   // row_mirror
  return v;
}

// f32 -> OCP e4m3fn, RTNE, |v| <= 1 (unit-norm rows)
__device__ __forceinline__ u8 f2e4m3(float v){
  unsigned s = (__float_as_uint(v) >> 24) & 0x80u;
  float a = fabsf(v);
  if (a < 0.0009765625f) return (u8)s;          // < 2^-10 -> 0
  if (a < 0.015625f){                            // denormal: quanta 2^-9
    int q = (int)rintf(a * 512.0f);              // RTNE, 1..8 (8 -> 0x08 = 2^-6)
    return (u8)(s | (unsigned)q);
  }
  unsigned u = __float_as_uint(a);
  int E = (int)(u >> 23) - 127;                  // -6..0
  unsigned m = u & 0x7FFFFF;
  unsigned mant = m >> 20;
  unsigned rem  = m & 0xFFFFF;
  mant += (rem > 0x80000u || (rem == 0x80000u && (mant & 1u))) ? 1u : 0u;
  if (mant == 8u){ mant = 0u; E += 1; }
  return (u8)(s | ((unsigned)(E + 7) << 3) | mant);
}

// --- Kernel 1: L2-normalize rows -> fp8 e4m3, pre-swizzled layout -----------
// Per row, each BK=64 unit (64 B) holds logical 8B k-groups g=0..7 arranged as
// 16B chunks c=0..3 containing groups {c, c+4}; chunk c stored at c^((row>>1)&3).
// k_gemm stages 64B units linearly (global_load_lds) and reads b128 at chunk
// (g ^ ((lrow>>1)&3)) -> returns k-step0 (8B) + k-step1 (8B); byte-geometry
// identical to the round-3..7-verified conflict-free swizzle.
__global__ __launch_bounds__(256) void k_normalize(const float* __restrict__ x,
                                                   u8* __restrict__ q){
  const int row  = blockIdx.x * 4 + (threadIdx.x >> 6);
  const int lane = threadIdx.x & 63;
  const float* xr = x + (size_t)row * DIM + lane * 8;
  float4 a = *(const float4*)xr;
  float4 b = *(const float4*)(xr + 4);
  float s = a.x*a.x + a.y*a.y + a.z*a.z + a.w*a.w
          + b.x*b.x + b.y*b.y + b.z*b.z + b.w*b.w;
  #pragma unroll
  for (int m = 1; m < 64; m <<= 1) s += __shfl_xor(s, m);
  const float inv = 1.0f / fmaxf(sqrtf(s), 1e-12f);
  float f[8] = {a.x, a.y, a.z, a.w, b.x, b.y, b.z, b.w};
  union { u8 b[8]; unsigned long long u; } pk;
  #pragma unroll
  for (int e = 0; e < 8; e++) pk.b[e] = f2e4m3(f[e] * inv);
  const int kb = lane >> 3;                 // BK-unit 0..7
  const int g  = lane & 7;                  // logical 8B k-group
  const int sw = (row >> 1) & 3;
  const size_t off = (size_t)row * DIM + kb * 64
                   + (size_t)(((g & 3) ^ sw) * 16 + (g >> 2) * 8);
  *(unsigned long long*)(q + off) = pk.u;
}

// --- Kernel 2: fp8 GEMM, 256r x 128c units (round-4-verified geometry) ------
// 4 waves (2x2), wave tile 128x64 = 8x4 frags of 16x16x32 fp8. BK=64 dbuf
// (A 2x16KB + B 2x8KB = 48KB -> 2 blk/CU). Stage-early + single __syncthreads
// per K-tile. One b128 ds_read per frag feeds BOTH k-steps (half the reads of
// the fp16 version). Slots: row path J*2+wc in [4I,128); mirror (J>=2I+2)
// I*4+wr*2+h in [0,4I) -> complete, write-once, deterministic (r4-verified).
__global__ __launch_bounds__(256, 2) void k_gemm(const u8* __restrict__ q,
                                                 const int* __restrict__ labels,
                                                 float* __restrict__ ppos,
                                                 float* __restrict__ ptot){
  __shared__ u8 sA[2][256 * 64];    // 2 x 16 KB
  __shared__ u8 sB[2][128 * 64];    // 2 x 8 KB
  __shared__ int labI[256], labJ[128];

  // XCD swizzle (1056 = 8 x 132, bijective) + r4 decode
  const int bid = (blockIdx.x & 7) * 132 + (blockIdx.x >> 3);
  int I = (int)((65.0f - sqrtf(4225.0f - 4.0f * (float)bid)) * 0.5f);
  while ((I + 1) * (64 - I) <= bid) I++;
  while (I * (65 - I) > bid) I--;
  const int J = 2 * I + (bid - I * (65 - I));
  const bool mirror = (J >= 2 * I + 2);
  const int rowbase = I * 256, colbase = J * 128;

  const int t    = threadIdx.x;
  const int lane = t & 63;
  const int w    = t >> 6;
  const int wr   = w >> 1, wc = w & 1;
  const int lrow = lane & 15;
  const int g    = lane >> 4;

  labI[t] = labels[rowbase + t];
  if (t < 128) labJ[t] = labels[colbase + t];

  // swizzled chunk16 byte offset within a 64B row-unit
  const int gs = (g ^ ((lrow >> 1) & 3)) * 16;
  int ra[8], rb[4];
  #pragma unroll
  for (int m = 0; m < 8; m++) ra[m] = (wr * 128 + m * 16 + lrow) * 64 + gs;
  #pragma unroll
  for (int n = 0; n < 4; n++) rb[n] = (wc * 64 + n * 16 + lrow) * 64 + gs;

  // staging: thread t covers row (t>>2) (+64/shot), phys chunk16 (t&3)
  const u8* srcA = q + (size_t)(rowbase + (t >> 2)) * DIM + (t & 3) * 16;
  const u8* srcB = q + (size_t)(colbase + (t >> 2)) * DIM + (t & 3) * 16;
  const int dL = t * 16;

#define STAGE(BUF, KT) do{                                                \
    gload_lds16(srcA + (KT) * 64,                  sA[BUF] + dL);         \
    gload_lds16(srcA + (KT) * 64 +  64 * DIM,      sA[BUF] + dL + 4096);  \
    gload_lds16(srcA + (KT) * 64 + 128 * DIM,      sA[BUF] + dL + 8192);  \
    gload_lds16(srcA + (KT) * 64 + 192 * DIM,      sA[BUF] + dL + 12288); \
    gload_lds16(srcB + (KT) * 64,                  sB[BUF] + dL);         \
    gload_lds16(srcB + (KT) * 64 +  64 * DIM,      sB[BUF] + dL + 4096);  \
  }while(0)

  f32x4 acc[8][4];
  #pragma unroll
  for (int m = 0; m < 8; m++)
    #pragma unroll
    for (int n = 0; n < 4; n++)
      acc[m][n] = (f32x4){0.f, 0.f, 0.f, 0.f};

  STAGE(0, 0);
  __syncthreads();

  for (int kt = 0; kt < 8; ++kt){
    const int cur = kt & 1;
    if (kt < 7) STAGE(cur ^ 1, kt + 1);        // issue next tile early
    const u8* pA = sA[cur];
    const u8* pB = sB[cur];
    long2_t av[8], bv[4];
    #pragma unroll
    for (int n = 0; n < 4; n++) bv[n] = *(const long2_t*)(pB + rb[n]);
    #pragma unroll
    for (int m = 0; m < 8; m++) av[m] = *(const long2_t*)(pA + ra[m]);
    #pragma unroll
    for (int m = 0; m < 8; m++)
      #pragma unroll
      for (int n = 0; n < 4; n++)
        acc[m][n] = __builtin_amdgcn_mfma_f32_16x16x32_fp8_fp8(
            av[m][0], bv[n][0], acc[m][n], 0, 0, 0);
    #pragma unroll
    for (int m = 0; m < 8; m++)
      #pragma unroll
      for (int n = 0; n < 4; n++)
        acc[m][n] = __builtin_amdgcn_mfma_f32_16x16x32_fp8_fp8(
            av[m][1], bv[n][1], acc[m][n], 0, 0, 0);
    __syncthreads();                           // drains vmcnt (loads ~1 tile old)
  }
#undef STAGE

  const int i0 = rowbase + wr * 128;
  const int j0 = colbase + wc * 64;

  int li_[8][4], lj_[4];
  #pragma unroll
  for (int m = 0; m < 8; m++)
    #pragma unroll
    for (int e = 0; e < 4; e++)
      li_[m][e] = labI[wr * 128 + m * 16 + g * 4 + e];
  #pragma unroll
  for (int n = 0; n < 4; n++)
    lj_[n] = labJ[wc * 64 + n * 16 + lrow];

  const float invT = 14.285714285714286f;  // 1/0.07
  #pragma unroll
  for (int m = 0; m < 8; m++)
    #pragma unroll
    for (int n = 0; n < 4; n++)
      #pragma unroll
      for (int e = 0; e < 4; e++){
        int i = i0 + m * 16 + g * 4 + e;
        int j = j0 + n * 16 + lrow;
        acc[m][n][e] = (i == j) ? 0.0f : __expf(acc[m][n][e] * invT);
      }

  // row sums -> slot J*2 + wc (DPP reduce, VALU-only)
  {
    float* pp = ppos + (size_t)(J * 2 + wc) * BATCH;
    float* pt = ptot + (size_t)(J * 2 + wc) * BATCH;
    #pragma unroll
    for (int m = 0; m < 8; m++){
      float tr[4] = {0, 0, 0, 0}, pr[4] = {0, 0, 0, 0};
      #pragma unroll
      for (int n = 0; n < 4; n++){
        int lj = lj_[n];
        #pragma unroll
        for (int e = 0; e < 4; e++){
          float v = acc[m][n][e];
          tr[e] += v;
          pr[e] += (li_[m][e] == lj) ? v : 0.0f;
        }
      }
      #pragma unroll
      for (int e = 0; e < 4; e++){
        tr[e] = red16(tr[e]);
        pr[e] = red16(pr[e]);
      }
      if (lrow == 0){
        int ib = i0 + m * 16 + g * 4;
        #pragma unroll
        for (int e = 0; e < 4; e++){
          pt[ib + e] = tr[e];
          pp[ib + e] = pr[e];
        }
      }
    }
  }

  // col sums via symmetry -> slots I*4 + wr*2 + h
  if (mirror){
    #pragma unroll
    for (int h = 0; h < 2; h++){
      float* pp = ppos + (size_t)(I * 4 + wr * 2 + h) * BATCH;
      float* pt = ptot + (size_t)(I * 4 + wr * 2 + h) * BATCH;
      #pragma unroll
      for (int n = 0; n < 4; n++){
        float ts = 0.f, ps = 0.f;
        int lj = lj_[n];
        #pragma unroll
        for (int m = h * 4; m < h * 4 + 4; m++)
          #pragma unroll
          for (int e = 0; e < 4; e++){
            float v = acc[m][n][e];
            ts += v;
            ps += (li_[m][e] == lj) ? v : 0.0f;
          }
        ts += __shfl_xor(ts, 16); ps += __shfl_xor(ps, 16);
        ts += __shfl_xor(ts, 32); ps += __shfl_xor(ps, 32);
        if (lane < 16){
          int j = j0 + n * 16 + lane;
          pt[j] = ts;
          pp[j] = ps;
        }
      }
    }
  }
}

// --- Kernel 3: per-row loss, 256 blocks (32 rows each), coalesced -----------
__global__ __launch_bounds__(256) void k_rowloss(const float* __restrict__ ppos,
                                                 const float* __restrict__ ptot,
                                                 float* __restrict__ bsum){
  __shared__ float sp[256], st2[256];
  const int t = threadIdx.x;
  const int r = blockIdx.x * 32 + (t & 31);
  const int c0 = t >> 5;                      // 0..7
  float p = 0.f, tt = 0.f;
  for (int c = c0; c < 128; c += 8){
    p  += ppos[(size_t)c * BATCH + r];
    tt += ptot[(size_t)c * BATCH + r];
  }
  sp[t] = p; st2[t] = tt;
  __syncthreads();
  if (t < 32){
    float P = 0.f, T = 0.f;
    #pragma unroll
    for (int k = 0; k < 8; k++){ P += sp[t + k * 32]; T += st2[t + k * 32]; }
    sp[t] = -logf(P / (T + 1e-8f));
  }
  __syncthreads();
  if (t == 0){
    float s = 0.f;
    #pragma unroll
    for (int k = 0; k < 32; k++) s += sp[k];
    bsum[blockIdx.x] = s;
  }
}

// --- Kernel 4: final mean over 256 block sums -------------------------------
__global__ __launch_bounds__(256) void k_final(const float* __restrict__ bsum,
                                               float* __restrict__ out){
  __shared__ float s4[4];
  float v = bsum[threadIdx.x];
  #pragma unroll
  for (int m = 1; m < 64; m <<= 1) v += __shfl_xor(v, m);
  if ((threadIdx.x & 63) == 0) s4[threadIdx.x >> 6] = v;
  __syncthreads();
  if (threadIdx.x == 0) out[0] = (s4[0] + s4[1] + s4[2] + s4[3]) * (1.0f / 8192.0f);
}

extern "C" void kernel_launch(void* const* d_in, const int* in_sizes, int n_in,
                              void* d_out, int out_size, void* d_ws, size_t ws_size,
                              hipStream_t stream){
  const float* x      = (const float*)d_in[0];
  const int*   labels = (const int*)d_in[1];
  float*       out    = (float*)d_out;

  char* ws = (char*)d_ws;
  u8*    q    = (u8*)ws;                             //  4,194,304 B (8192x512 fp8)
  float* ppos = (float*)(ws + 8388608);              //  4,194,304 B (128 x 8192 f32)
  float* ptot = (float*)(ws + 8388608 + 4194304);    //  4,194,304 B
  float* bsum = (float*)(ws + 8388608 + 8388608);    //      1,024 B

  k_normalize<<<BATCH / 4, 256, 0, stream>>>(x, q);
  k_gemm<<<NBLK, 256, 0, stream>>>(q, labels, ppos, ptot);
  k_rowloss<<<256, 256, 0, stream>>>(ppos, ptot, bsum);
  k_final<<<1, 256, 0, stream>>>(bsum, out);
}

// Round 9
// 56.149 us; speedup vs baseline: 1.9482x; 1.0606x over previous
//
#include <hip/hip_runtime.h>

#define BATCH 8192
#define DIM   512
#define NBLK  2080                 // 64x64 grid of 128^2 tiles, bi <= bj

typedef __attribute__((ext_vector_type(2))) long long2_t;
typedef __attribute__((ext_vector_type(4))) float f32x4;
typedef unsigned char u8;

// async global->LDS, 16B per lane; LDS dest = wave-uniform base + lane*16
__device__ __forceinline__ void gload_lds16(const void* g, void* l){
  __builtin_amdgcn_global_load_lds(
      (const __attribute__((address_space(1))) void*)g,
      (__attribute__((address_space(3))) void*)l, 16, 0, 0);
}

// VALU-only 16-lane-group sum via DPP (verified r7/r8)
template<int CTRL>
__device__ __forceinline__ float dpp_add(float v){
  int s = __builtin_amdgcn_update_dpp(0, __float_as_int(v), CTRL, 0xF, 0xF, true);
  return v + __int_as_float(s);
}
__device__ __forceinline__ float red16(float v){
  v = dpp_add<0xB1>(v);    // quad_perm [1,0,3,2]
  v = dpp_add<0x4E>(v);    // quad_perm [2,3,0,1]
  v = dpp_add<0x141>(v);   // row_half_mirror
  v = dpp_add<0x140>(v);   // row_mirror
  return v;
}

// f32 -> OCP e4m3fn, RTNE, |v| <= 1 (unit-norm rows) (verified r8)
__device__ __forceinline__ u8 f2e4m3(float v){
  unsigned s = (__float_as_uint(v) >> 24) & 0x80u;
  float a = fabsf(v);
  if (a < 0.0009765625f) return (u8)s;
  if (a < 0.015625f){
    int qd = (int)rintf(a * 512.0f);
    return (u8)(s | (unsigned)qd);
  }
  unsigned u = __float_as_uint(a);
  int E = (int)(u >> 23) - 127;
  unsigned m = u & 0x7FFFFF;
  unsigned mant = m >> 20;
  unsigned rem  = m & 0xFFFFF;
  mant += (rem > 0x80000u || (rem == 0x80000u && (mant & 1u))) ? 1u : 0u;
  if (mant == 8u){ mant = 0u; E += 1; }
  return (u8)(s | ((unsigned)(E + 7) << 3) | mant);
}

// --- Kernel 1: L2-normalize rows -> fp8 e4m3, pre-swizzled layout (r8) ------
__global__ __launch_bounds__(256) void k_normalize(const float* __restrict__ x,
                                                   u8* __restrict__ q){
  const int row  = blockIdx.x * 4 + (threadIdx.x >> 6);
  const int lane = threadIdx.x & 63;
  const float* xr = x + (size_t)row * DIM + lane * 8;
  float4 a = *(const float4*)xr;
  float4 b = *(const float4*)(xr + 4);
  float s = a.x*a.x + a.y*a.y + a.z*a.z + a.w*a.w
          + b.x*b.x + b.y*b.y + b.z*b.z + b.w*b.w;
  #pragma unroll
  for (int m = 1; m < 64; m <<= 1) s += __shfl_xor(s, m);
  const float inv = 1.0f / fmaxf(sqrtf(s), 1e-12f);
  float f[8] = {a.x, a.y, a.z, a.w, b.x, b.y, b.z, b.w};
  union { u8 b[8]; unsigned long long u; } pk;
  #pragma unroll
  for (int e = 0; e < 8; e++) pk.b[e] = f2e4m3(f[e] * inv);
  const int kb = lane >> 3;                 // BK-unit 0..7
  const int g  = lane & 7;                  // logical 8B k-group
  const int sw = (row >> 1) & 3;
  const size_t off = (size_t)row * DIM + kb * 64
                   + (size_t)(((g & 3) ^ sw) * 16 + (g >> 2) * 8);
  *(unsigned long long*)(q + off) = pk.u;
}

// --- Kernel 2: fp8 GEMM, 128x128 tiles, 3 blocks/CU -------------------------
// 4 waves (2x2), wave tile 64x64 = 4x4 frags of 16x16x32 fp8 (one b128
// ds_read per frag feeds both k-halves). BK=64 dbuf (32KB) + 8KB dynamic-LDS
// pad -> exactly 3 blocks/CU (12 waves). 2080 tiles / 768 slots = 2.71 ->
// last round 71% full (vs r8's 6%). Slots (r2/r3-verified algebra): row path
// 2*bj+wc covers [2*bi,128); mirror (bi<bj) 2*bi+wr covers [0,2*bj) ->
// complete, write-once, deterministic.
__global__ __launch_bounds__(256, 3) void k_gemm(const u8* __restrict__ q,
                                                 const int* __restrict__ labels,
                                                 float* __restrict__ ppos,
                                                 float* __restrict__ ptot){
  __shared__ u8 sA[2][128 * 64];    // 2 x 8 KB
  __shared__ u8 sB[2][128 * 64];    // 2 x 8 KB
  __shared__ int labI[128], labJ[128];

  // XCD swizzle (2080 = 8 x 260, bijective) + triangular decode (r2-verified)
  const int bid = (blockIdx.x & 7) * 260 + (blockIdx.x >> 3);
  int bj = (int)((sqrtf(8.0f * (float)bid + 1.0f) - 1.0f) * 0.5f);
  while ((bj + 1) * (bj + 2) / 2 <= bid) bj++;
  while (bj * (bj + 1) / 2 > bid) bj--;
  const int bi = bid - bj * (bj + 1) / 2;
  const bool mirror = (bi != bj);
  const int rowbase = bi * 128, colbase = bj * 128;

  const int t    = threadIdx.x;
  const int lane = t & 63;
  const int w    = t >> 6;
  const int wr   = w >> 1, wc = w & 1;
  const int lrow = lane & 15;
  const int g    = lane >> 4;

  if (t < 128) labI[t] = labels[rowbase + t];
  else         labJ[t - 128] = labels[colbase + (t - 128)];

  // swizzled chunk16 byte offset within a 64B row-unit (r8-verified)
  const int gs = (g ^ ((lrow >> 1) & 3)) * 16;
  int ra[4], rb[4];
  #pragma unroll
  for (int m = 0; m < 4; m++) ra[m] = (wr * 64 + m * 16 + lrow) * 64 + gs;
  #pragma unroll
  for (int n = 0; n < 4; n++) rb[n] = (wc * 64 + n * 16 + lrow) * 64 + gs;

  // staging: thread t covers row (t>>2) (+64/shot), phys chunk16 (t&3)
  const u8* srcA = q + (size_t)(rowbase + (t >> 2)) * DIM + (t & 3) * 16;
  const u8* srcB = q + (size_t)(colbase + (t >> 2)) * DIM + (t & 3) * 16;
  const int dL = t * 16;

#define STAGE(BUF, KT) do{                                                \
    gload_lds16(srcA + (KT) * 64,             sA[BUF] + dL);              \
    gload_lds16(srcA + (KT) * 64 + 64 * DIM,  sA[BUF] + dL + 4096);       \
    gload_lds16(srcB + (KT) * 64,             sB[BUF] + dL);              \
    gload_lds16(srcB + (KT) * 64 + 64 * DIM,  sB[BUF] + dL + 4096);       \
  }while(0)

  f32x4 acc[4][4];
  #pragma unroll
  for (int m = 0; m < 4; m++)
    #pragma unroll
    for (int n = 0; n < 4; n++)
      acc[m][n] = (f32x4){0.f, 0.f, 0.f, 0.f};

  STAGE(0, 0);
  __syncthreads();

  for (int kt = 0; kt < 8; ++kt){
    const int cur = kt & 1;
    if (kt < 7) STAGE(cur ^ 1, kt + 1);        // issue next tile early
    const u8* pA = sA[cur];
    const u8* pB = sB[cur];
    long2_t av[4], bv[4];
    #pragma unroll
    for (int n = 0; n < 4; n++) bv[n] = *(const long2_t*)(pB + rb[n]);
    #pragma unroll
    for (int m = 0; m < 4; m++) av[m] = *(const long2_t*)(pA + ra[m]);
    #pragma unroll
    for (int m = 0; m < 4; m++)
      #pragma unroll
      for (int n = 0; n < 4; n++)
        acc[m][n] = __builtin_amdgcn_mfma_f32_16x16x32_fp8_fp8(
            av[m][0], bv[n][0], acc[m][n], 0, 0, 0);
    #pragma unroll
    for (int m = 0; m < 4; m++)
      #pragma unroll
      for (int n = 0; n < 4; n++)
        acc[m][n] = __builtin_amdgcn_mfma_f32_16x16x32_fp8_fp8(
            av[m][1], bv[n][1], acc[m][n], 0, 0, 0);
    __syncthreads();                           // drains vmcnt (loads ~1 tile old)
  }
#undef STAGE

  const int i0 = rowbase + wr * 64;
  const int j0 = colbase + wc * 64;

  int li_[4][4], lj_[4];
  #pragma unroll
  for (int m = 0; m < 4; m++)
    #pragma unroll
    for (int e = 0; e < 4; e++)
      li_[m][e] = labI[wr * 64 + m * 16 + g * 4 + e];
  #pragma unroll
  for (int n = 0; n < 4; n++)
    lj_[n] = labJ[wc * 64 + n * 16 + lrow];

  const float invT = 14.285714285714286f;  // 1/0.07
  #pragma unroll
  for (int m = 0; m < 4; m++)
    #pragma unroll
    for (int n = 0; n < 4; n++)
      #pragma unroll
      for (int e = 0; e < 4; e++){
        int i = i0 + m * 16 + g * 4 + e;
        int j = j0 + n * 16 + lrow;
        acc[m][n][e] = (i == j) ? 0.0f : __expf(acc[m][n][e] * invT);
      }

  // row sums -> slot 2*bj + wc (DPP reduce, VALU-only)
  {
    float* pp = ppos + (size_t)(2 * bj + wc) * BATCH;
    float* pt = ptot + (size_t)(2 * bj + wc) * BATCH;
    #pragma unroll
    for (int m = 0; m < 4; m++){
      float tr[4] = {0, 0, 0, 0}, pr[4] = {0, 0, 0, 0};
      #pragma unroll
      for (int n = 0; n < 4; n++){
        int lj = lj_[n];
        #pragma unroll
        for (int e = 0; e < 4; e++){
          float v = acc[m][n][e];
          tr[e] += v;
          pr[e] += (li_[m][e] == lj) ? v : 0.0f;
        }
      }
      #pragma unroll
      for (int e = 0; e < 4; e++){
        tr[e] = red16(tr[e]);
        pr[e] = red16(pr[e]);
      }
      if (lrow == 0){
        int ib = i0 + m * 16 + g * 4;
        #pragma unroll
        for (int e = 0; e < 4; e++){
          pt[ib + e] = tr[e];
          pp[ib + e] = pr[e];
        }
      }
    }
  }

  // col sums via symmetry -> slot 2*bi + wr
  if (mirror){
    float* pp = ppos + (size_t)(2 * bi + wr) * BATCH;
    float* pt = ptot + (size_t)(2 * bi + wr) * BATCH;
    #pragma unroll
    for (int n = 0; n < 4; n++){
      float ts = 0.f, ps = 0.f;
      int lj = lj_[n];
      #pragma unroll
      for (int m = 0; m < 4; m++)
        #pragma unroll
        for (int e = 0; e < 4; e++){
          float v = acc[m][n][e];
          ts += v;
          ps += (li_[m][e] == lj) ? v : 0.0f;
        }
      ts += __shfl_xor(ts, 16); ps += __shfl_xor(ps, 16);
      ts += __shfl_xor(ts, 32); ps += __shfl_xor(ps, 32);
      if (lane < 16){
        int j = j0 + n * 16 + lane;
        pt[j] = ts;
        pp[j] = ps;
      }
    }
  }
}

// --- Kernel 3: per-row loss, 256 blocks (32 rows each), coalesced -----------
__global__ __launch_bounds__(256) void k_rowloss(const float* __restrict__ ppos,
                                                 const float* __restrict__ ptot,
                                                 float* __restrict__ bsum){
  __shared__ float sp[256], st2[256];
  const int t = threadIdx.x;
  const int r = blockIdx.x * 32 + (t & 31);
  const int c0 = t >> 5;                      // 0..7
  float p = 0.f, tt = 0.f;
  for (int c = c0; c < 128; c += 8){
    p  += ppos[(size_t)c * BATCH + r];
    tt += ptot[(size_t)c * BATCH + r];
  }
  sp[t] = p; st2[t] = tt;
  __syncthreads();
  if (t < 32){
    float P = 0.f, T = 0.f;
    #pragma unroll
    for (int k = 0; k < 8; k++){ P += sp[t + k * 32]; T += st2[t + k * 32]; }
    sp[t] = -logf(P / (T + 1e-8f));
  }
  __syncthreads();
  if (t == 0){
    float s = 0.f;
    #pragma unroll
    for (int k = 0; k < 32; k++) s += sp[k];
    bsum[blockIdx.x] = s;
  }
}

// --- Kernel 4: final mean over 256 block sums -------------------------------
__global__ __launch_bounds__(256) void k_final(const float* __restrict__ bsum,
                                               float* __restrict__ out){
  __shared__ float s4[4];
  float v = bsum[threadIdx.x];
  #pragma unroll
  for (int m = 1; m < 64; m <<= 1) v += __shfl_xor(v, m);
  if ((threadIdx.x & 63) == 0) s4[threadIdx.x >> 6] = v;
  __syncthreads();
  if (threadIdx.x == 0) out[0] = (s4[0] + s4[1] + s4[2] + s4[3]) * (1.0f / 8192.0f);
}

extern "C" void kernel_launch(void* const* d_in, const int* in_sizes, int n_in,
                              void* d_out, int out_size, void* d_ws, size_t ws_size,
                              hipStream_t stream){
  const float* x      = (const float*)d_in[0];
  const int*   labels = (const int*)d_in[1];
  float*       out    = (float*)d_out;

  char* ws = (char*)d_ws;
  u8*    q    = (u8*)ws;                             //  4,194,304 B (8192x512 fp8)
  float* ppos = (float*)(ws + 8388608);              //  4,194,304 B (128 x 8192 f32)
  float* ptot = (float*)(ws + 8388608 + 4194304);    //  4,194,304 B
  float* bsum = (float*)(ws + 8388608 + 8388608);    //      1,024 B

  k_normalize<<<BATCH / 4, 256, 0, stream>>>(x, q);
  // 8192 B dynamic LDS pad: static 33KB + 8KB = 41KB -> exactly 3 blocks/CU
  k_gemm<<<NBLK, 256, 8192, stream>>>(q, labels, ppos, ptot);
  k_rowloss<<<256, 256, 0, stream>>>(ppos, ptot, bsum);
  k_final<<<1, 256, 0, stream>>>(bsum, out);
}